// Round 5
// baseline (1821.979 us; speedup 1.0000x reference)
//
#include <hip/hip_runtime.h>
#include <math.h>

#define MSZ   1048576ull  // 1024*1024 elements per matrix slot
#define NMAT  33          // matrix 0 = L0, matrices 1..32 = per-batch L
#define PANSZ 61440       // 960*64 shorts per matrix per panel plane

__device__ __forceinline__ float frcp(float x){ return __builtin_amdgcn_rcpf(x); }

typedef __attribute__((ext_vector_type(8)))  short  bfrag;   // 8 x bf16 (4 VGPR)
typedef __attribute__((ext_vector_type(8)))  unsigned short u16x8;
typedef __attribute__((ext_vector_type(16))) float  f32x16;  // 32x32 acc

__device__ __forceinline__ unsigned short bf16rn(float x){
  unsigned u = __float_as_uint(x);
  unsigned r = u + 0x7fffu + ((u>>16)&1u);
  return (unsigned short)(r>>16);
}
__device__ __forceinline__ float bf2f(unsigned short h){
  return __uint_as_float(((unsigned)h)<<16);
}

// ---------------------------------------------------------------- setup
// blocks 0..3: V = softmax(Vc)    blocks 4..4099: Ws = symmetrized sigmoid(W)
__global__ void k_misc(const float* __restrict__ Vc, float* __restrict__ V,
                       const float* __restrict__ W, float* __restrict__ Ws){
  int t = threadIdx.x;
  if(blockIdx.x < 4){
    int i = blockIdx.x*256 + t;
    float4 v = ((const float4*)Vc)[i];
    float mx = fmaxf(fmaxf(v.x,v.y), fmaxf(v.z,v.w));
    float e0=__expf(v.x-mx), e1=__expf(v.y-mx), e2=__expf(v.z-mx), e3=__expf(v.w-mx);
    float is = 1.f/(e0+e1+e2+e3);
    ((float4*)V)[i] = make_float4(e0*is, e1*is, e2*is, e3*is);
  } else {
    int idx = (blockIdx.x-4)*256 + t;
    int i = idx>>10, j = idx&1023;
    float v = 0.f;
    if(i != j){
      float w = (i>j) ? W[i*1024+j] : W[j*1024+i];
      v = 1.f/(1.f+__expf(-w));
    }
    Ws[idx]=v;
  }
}

__global__ void k_pr_y(const float* __restrict__ V, const int* __restrict__ x,
                       float* __restrict__ PrInv, float* __restrict__ y){
  int b = blockIdx.x, t = threadIdx.x;
  __shared__ float red[256];
  float acc = 0.f;
  for(int i=t; i<1024; i+=256){
    int xv = x[b*1024+i];
    float pr = V[i*4+xv];
    PrInv[b*1024+i] = 1.f/pr;
    acc += logf(pr + 1e-7f);
  }
  red[t]=acc; __syncthreads();
  for(int s=128;s>0;s>>=1){ if(t<s) red[t]+=red[t+s]; __syncthreads(); }
  if(t==0) y[b]=red[0];
}

// ---------------------------------------------------------------- sinkhorn + WP
// 20 iters (4x4 Sinkhorn contracts ~0.2/iter; converged << fp32 ulp by 20).
// Writes FINAL off-diagonal Laplacian form 1e-7 - val directly; per-(b,row)
// partial sums (for the diagonal) wave-reduced into `partial` (16 slots/row).
__global__ void __launch_bounds__(256) k_sinkhorn(
    const float* __restrict__ Ec, const float* __restrict__ V,
    const float* __restrict__ Ws, const float* __restrict__ PrInv,
    const int* __restrict__ x, float* __restrict__ mats,
    float* __restrict__ partial){
  int idx = blockIdx.x*256 + threadIdx.x;
  int i = idx>>10, j = idx&1023;   // block covers fixed i, 256 consecutive j
  if(i==0) return;                 // row 0 of WP never needed (whole blocks)
  int t = threadIdx.x;
  int lane = t & 63, wv = t >> 6;
  __shared__ float sE[256][17];
  float E[16];
  {
    const float4* p = (const float4*)(Ec + (size_t)idx*16);
    float4 q0=p[0], q1=p[1], q2=p[2], q3=p[3];
    E[0]=__expf(q0.x); E[1]=__expf(q0.y); E[2]=__expf(q0.z); E[3]=__expf(q0.w);
    E[4]=__expf(q1.x); E[5]=__expf(q1.y); E[6]=__expf(q1.z); E[7]=__expf(q1.w);
    E[8]=__expf(q2.x); E[9]=__expf(q2.y); E[10]=__expf(q2.z); E[11]=__expf(q2.w);
    E[12]=__expf(q3.x);E[13]=__expf(q3.y);E[14]=__expf(q3.z); E[15]=__expf(q3.w);
  }
  float s0=0.f;
  #pragma unroll
  for(int q=0;q<16;q++) s0+=E[q];
  float is0 = frcp(s0);
  #pragma unroll
  for(int q=0;q<16;q++) E[q]*=is0;
  float av[4], bv[4];
  {
    float4 va = ((const float4*)V)[i];
    av[0]=va.x; av[1]=va.y; av[2]=va.z; av[3]=va.w;
    float4 vb = ((const float4*)V)[j];
    bv[0]=vb.x; bv[1]=vb.y; bv[2]=vb.z; bv[3]=vb.w;
  }
  for(int it=0; it<20; ++it){
    #pragma unroll
    for(int r=0;r<4;r++){
      float rs = E[4*r]+E[4*r+1]+E[4*r+2]+E[4*r+3];
      float sc = av[r]*frcp(rs+1e-7f);
      E[4*r]*=sc; E[4*r+1]*=sc; E[4*r+2]*=sc; E[4*r+3]*=sc;
    }
    #pragma unroll
    for(int c=0;c<4;c++){
      float cs = E[c]+E[4+c]+E[8+c]+E[12+c];
      float sc = bv[c]*frcp(cs+1e-7f);
      E[c]*=sc; E[4+c]*=sc; E[8+c]*=sc; E[12+c]*=sc;
    }
  }
  #pragma unroll
  for(int q=0;q<16;q++) sE[t][q] = fminf(fmaxf(E[q],0.f),1.f);
  float wsij = Ws[idx];                 // 0 on diagonal -> val=0 there
  for(int b=0;b<32;b++){
    int xi = x[b*1024+i];               // uniform per block -> scalar load
    int xj = x[b*1024+j];
    float val = sE[t][(xi<<2)+xj] * wsij * PrInv[b*1024+i] * PrInv[b*1024+j];
    if(j!=0)                            // j==0 exists only in the row sum
      mats[(size_t)(1+b)*MSZ + (size_t)(i-1)*1024 + (j-1)] = 1e-7f - val;
    float r = val;                      // wave-reduce row-sum contribution
    r += __shfl_down(r,32); r += __shfl_down(r,16); r += __shfl_down(r,8);
    r += __shfl_down(r,4);  r += __shfl_down(r,2);  r += __shfl_down(r,1);
    if(lane==0)
      partial[((size_t)b<<14) + ((size_t)(i-1)<<4) + ((blockIdx.x&3)<<2) + wv] = r;
  }
}

// ---------------------------------------------------------------- L0 build
// mats[0] = L0[1:,1:] padded to 1024 (row/col 1023 zero, [1023][1023]=1).
__global__ void k_l0(const float* __restrict__ Ws, float* __restrict__ mats){
  int r = blockIdx.x, t = threadIdx.x;
  float* orow = mats + (size_t)r*1024;
  if(r == 1023){
    float4 o = make_float4(0.f,0.f,0.f,0.f);
    if(t==255) o.w = 1.f;
    ((float4*)orow)[t] = o;
    return;
  }
  const float* wrow = Ws + (size_t)(r+1)*1024;
  float4 v = ((const float4*)wrow)[t];
  __shared__ float red[256];
  red[t] = v.x+v.y+v.z+v.w;             // full 1024-col row sum (Ws diag = 0)
  __syncthreads();
  for(int s=128;s>0;s>>=1){ if(t<s) red[t]+=red[t+s]; __syncthreads(); }
  float rs = red[0];
  float o[4];
  #pragma unroll
  for(int q=0;q<4;q++){
    int c = 4*t+q;
    if(c==r)          o[q] = rs + 1e-7f;
    else if(c < 1023) o[q] = 1e-7f - wrow[c+1];
    else              o[q] = 0.f;
  }
  ((float4*)orow)[t] = make_float4(o[0],o[1],o[2],o[3]);
}

// Patch batch matrices: diagonal = rowsum+1e-7 (from partials), clear padding.
__global__ void k_patch(float* __restrict__ mats, const float* __restrict__ partial){
  int m = blockIdx.y + 1;
  int r = blockIdx.x*256 + threadIdx.x;   // 0..1023
  float* A = mats + (size_t)m*MSZ;
  A[(size_t)r*1024 + 1023] = (r==1023) ? 1.f : 0.f;   // col 1023 (+corner)
  if(r < 1023){
    A[(size_t)1023*1024 + r] = 0.f;                   // row 1023
    const float* pp = partial + (((size_t)(m-1))<<14) + ((size_t)r<<4);
    float s = 0.f;
    #pragma unroll
    for(int q=0;q<16;q++) s += pp[q];
    A[(size_t)r*1024 + r] = s + 1e-7f;
  }
}

// ---------------------------------------------------------------- blocked LU
// Step-0 diagonal factor only; steps 1..15 are embedded in k_gemm.
__global__ void __launch_bounds__(64) k_diag(float* __restrict__ mats,
    float* __restrict__ L11g, float* __restrict__ U11g,
    float* __restrict__ logdet){
  int m = blockIdx.x;
  const float* A = mats + (size_t)m*MSZ;
  int t = threadIdx.x;
  float row[64];
  #pragma unroll
  for(int q=0;q<64;q++)
    row[q] = A[(size_t)t*1024 + q];
  float slog = 0.f;
  #pragma unroll
  for(int c=0;c<64;c++){
    float piv = __shfl(row[c], c);
    slog += logf(fabsf(piv));
    float ip = frcp(piv);
    bool below = t > c;
    float lic = below ? row[c]*ip : 0.f;
    row[c] = below ? lic : row[c];
    if(below) L11g[m*4096 + t*64 + c] = lic;
    #pragma unroll
    for(int q=c+1;q<64;q++){
      float uq = __shfl(row[q], c);
      row[q] = fmaf(-lic, uq, row[q]);
    }
  }
  #pragma unroll
  for(int q=0;q<64;q++)
    U11g[m*4096 + t*64 + q] = (q>=t) ? row[q] : 0.f;
  if(t==0) logdet[m] = slog;
}

// Panel solves; outputs written ONLY as pre-split bf16 hi/lo panels in the
// gemm's [row][k] layout.
__global__ void __launch_bounds__(256) k_panel(float* __restrict__ mats,
    const float* __restrict__ L11g, const float* __restrict__ U11g,
    unsigned short* __restrict__ Ah, unsigned short* __restrict__ Al,
    unsigned short* __restrict__ Bh, unsigned short* __restrict__ Bl, int k){
  int m = blockIdx.y;
  float* A = mats + (size_t)m*MSZ;
  int rem = 1024 - (k+64);
  int nb = (rem + 255) >> 8;
  int t = threadIdx.x;
  float v[64];
  unsigned short* Ph; unsigned short* Pl; int rel; bool act;
  if((int)blockIdx.x < nb){
    // ---- L21 = A21 * U11^-1  (thread per trailing row)
    const float* __restrict__ U = U11g + m*4096;
    rel = blockIdx.x*256 + t;
    act = rel < rem;
    int i = k + 64 + rel;
    size_t base = (size_t)i*1024 + k;
    const float4* pb = (const float4*)(A + (act ? base : 0));
    #pragma unroll
    for(int q4=0;q4<16;q4++){
      float4 w = act ? pb[q4] : make_float4(0.f,0.f,0.f,0.f);
      v[4*q4]=w.x; v[4*q4+1]=w.y; v[4*q4+2]=w.z; v[4*q4+3]=w.w;
    }
    #pragma unroll
    for(int p=0;p<64;p++){
      float xp = v[p]*frcp(U[p*64+p]);
      v[p] = xp;
      #pragma unroll
      for(int q=p+1;q<64;q++) v[q] = fmaf(-xp, U[p*64+q], v[q]);
    }
    Ph = Ah + (size_t)m*PANSZ; Pl = Al + (size_t)m*PANSZ;
  } else {
    // ---- U12 = L11^-1 * A12  (thread per trailing column)
    const float* __restrict__ L = L11g + m*4096;
    rel = (blockIdx.x - nb)*256 + t;
    act = rel < rem;
    int col = k + 64 + rel;
    #pragma unroll
    for(int r=0;r<64;r++) v[r] = act ? A[(size_t)(k+r)*1024 + col] : 0.f;
    #pragma unroll
    for(int r=1;r<64;r++){
      float s = v[r];
      #pragma unroll
      for(int p=0;p<r;p++) s = fmaf(-L[r*64+p], v[p], s);
      v[r] = s;
    }
    Ph = Bh + (size_t)m*PANSZ; Pl = Bl + (size_t)m*PANSZ;
  }
  if(act){
    u16x8* ph = (u16x8*)(Ph + (size_t)rel*64);
    u16x8* pl = (u16x8*)(Pl + (size_t)rel*64);
    #pragma unroll
    for(int q8=0;q8<8;q8++){
      u16x8 h8, l8;
      #pragma unroll
      for(int e=0;e<8;e++){
        float xv = v[q8*8+e];
        unsigned short h = bf16rn(xv);
        h8[e] = h;
        l8[e] = bf16rn(xv - bf2f(h));
      }
      ph[q8] = h8;
      pl[q8] = l8;
    }
  }
}

// ------------------------------------------------------- MFMA split-bf16 Schur
// A22 -= L21 * U12.  128x128 C tile, 4 waves, K=64 single stage.
// Block (0,0) additionally factors the NEXT 64x64 diagonal block (its wave 0's
// quadrant) right after the RMW: values stashed in LDS during the epilogue,
// then the shuffle-LU runs in-registers and writes L11/U11/logdet for step k+64.
__global__ void __launch_bounds__(256) k_gemm(float* __restrict__ mats,
    const unsigned short* __restrict__ Ah, const unsigned short* __restrict__ Al,
    const unsigned short* __restrict__ Bh, const unsigned short* __restrict__ Bl,
    int k, float* __restrict__ L11g, float* __restrict__ U11g,
    float* __restrict__ logdet){
  int m = blockIdx.z;
  float* A = mats + (size_t)m*MSZ;
  int rem = 1024 - (k+64);
  int i0rel = blockIdx.y*128;
  int j0rel = blockIdx.x*128;
  __shared__ unsigned short As[2][8192];   // [hi/lo][row*64 + swz(koct)*8]
  __shared__ unsigned short Bs[2][8192];   // [hi/lo][col*64 + swz(koct)*8]
  float* stash = (float*)As;               // 64x68 fp32 diag stash (reused)
  int t = threadIdx.x;
  int lane = t & 63, wvi = t >> 6;
  int wr = wvi >> 1, wc = wvi & 1;
  bool diagBlk = (blockIdx.x==0) & (blockIdx.y==0);
  bool dstash = diagBlk & (wvi==0);

  const unsigned short* pAh = Ah + (size_t)m*PANSZ;
  const unsigned short* pAl = Al + (size_t)m*PANSZ;
  const unsigned short* pBh = Bh + (size_t)m*PANSZ;
  const unsigned short* pBl = Bl + (size_t)m*PANSZ;

  #pragma unroll
  for(int p=0;p<4;p++){
    int c = t + 256*p;
    int row = c>>3, koct = c&7;
    int lo = row*64 + ((koct ^ (row&7))<<3);
    u16x8 z; z = 0;
    {
      int gr = i0rel + row;
      u16x8 vh = (gr<rem) ? *(const u16x8*)(pAh + (size_t)gr*64 + koct*8) : z;
      u16x8 vl = (gr<rem) ? *(const u16x8*)(pAl + (size_t)gr*64 + koct*8) : z;
      *(u16x8*)&As[0][lo] = vh;
      *(u16x8*)&As[1][lo] = vl;
    }
    {
      int gc = j0rel + row;
      u16x8 vh = (gc<rem) ? *(const u16x8*)(pBh + (size_t)gc*64 + koct*8) : z;
      u16x8 vl = (gc<rem) ? *(const u16x8*)(pBl + (size_t)gc*64 + koct*8) : z;
      *(u16x8*)&Bs[0][lo] = vh;
      *(u16x8*)&Bs[1][lo] = vl;
    }
  }
  __syncthreads();

  f32x16 acc[2][2];
  #pragma unroll
  for(int rt=0;rt<2;rt++)
    #pragma unroll
    for(int ct=0;ct<2;ct++)
      #pragma unroll
      for(int q=0;q<16;q++) acc[rt][ct][q] = 0.f;

  int kgrp = lane >> 5;
  #pragma unroll
  for(int kc=0;kc<4;kc++){
    int koct = kc*2 + kgrp;
    bfrag ah[2], al[2], bh[2], bl[2];
    #pragma unroll
    for(int rt=0;rt<2;rt++){
      int row = wr*64 + rt*32 + (lane&31);
      int ad = row*64 + ((koct ^ (row&7))<<3);
      ah[rt] = *(const bfrag*)&As[0][ad];
      al[rt] = *(const bfrag*)&As[1][ad];
    }
    #pragma unroll
    for(int ct=0;ct<2;ct++){
      int col = wc*64 + ct*32 + (lane&31);
      int ad = col*64 + ((koct ^ (col&7))<<3);
      bh[ct] = *(const bfrag*)&Bs[0][ad];
      bl[ct] = *(const bfrag*)&Bs[1][ad];
    }
    #pragma unroll
    for(int rt=0;rt<2;rt++)
      #pragma unroll
      for(int ct=0;ct<2;ct++){
        acc[rt][ct] = __builtin_amdgcn_mfma_f32_32x32x16_bf16(ah[rt], bh[ct], acc[rt][ct], 0,0,0);
        acc[rt][ct] = __builtin_amdgcn_mfma_f32_32x32x16_bf16(ah[rt], bl[ct], acc[rt][ct], 0,0,0);
        acc[rt][ct] = __builtin_amdgcn_mfma_f32_32x32x16_bf16(al[rt], bh[ct], acc[rt][ct], 0,0,0);
      }
  }

  __syncthreads();   // all LDS frag reads done before stash overwrites As

  // C RMW epilogue (C/D layout: col=lane&31, row=(reg&3)+8*(reg>>2)+4*(lane>>5))
  int r0 = k + 64;
  #pragma unroll
  for(int rt=0;rt<2;rt++){
    int rowblk = i0rel + wr*64 + rt*32;
    if(rowblk >= rem) continue;
    #pragma unroll
    for(int ct=0;ct<2;ct++){
      int colblk = j0rel + wc*64 + ct*32;
      if(colblk >= rem) continue;
      int col = r0 + colblk + (lane&31);
      int rbase = r0 + rowblk + ((lane>>5)<<2);
      #pragma unroll
      for(int reg=0;reg<16;reg++){
        int row = rbase + (reg&3) + ((reg>>2)<<3);
        float* pc = A + (size_t)row*1024 + col;
        float nv = *pc - acc[rt][ct][reg];
        *pc = nv;
        if(dstash){
          int lr = rt*32 + ((lane>>5)<<2) + (reg&3) + ((reg>>2)<<3);
          int lc = ct*32 + (lane&31);
          stash[lr*68 + lc] = nv;
        }
      }
    }
  }

  // ---- embedded next-step diagonal factor (wave 0 of block (0,0))
  if(dstash){
    float row[64];
    #pragma unroll
    for(int q4=0;q4<16;q4++){
      float4 v4 = *(const float4*)&stash[lane*68 + q4*4];
      row[q4*4]=v4.x; row[q4*4+1]=v4.y; row[q4*4+2]=v4.z; row[q4*4+3]=v4.w;
    }
    float slog = 0.f;
    #pragma unroll
    for(int c=0;c<64;c++){
      float piv = __shfl(row[c], c);
      slog += logf(fabsf(piv));
      float ip = frcp(piv);
      bool below = lane > c;
      float lic = below ? row[c]*ip : 0.f;
      row[c] = below ? lic : row[c];
      if(below) L11g[m*4096 + lane*64 + c] = lic;
      #pragma unroll
      for(int q=c+1;q<64;q++){
        float uq = __shfl(row[q], c);
        row[q] = fmaf(-lic, uq, row[q]);
      }
    }
    #pragma unroll
    for(int q=0;q<64;q++)
      U11g[m*4096 + lane*64 + q] = (q>=lane) ? row[q] : 0.f;
    if(lane==0) logdet[m] += slog;
  }
}

__global__ void k_final(const float* __restrict__ y, const float* __restrict__ logdet,
                        float* __restrict__ out){
  int b = threadIdx.x;
  if(b<32) out[b] = y[b] + logdet[1+b] - logdet[0];
}

// ---------------------------------------------------------------- launch
extern "C" void kernel_launch(void* const* d_in, const int* in_sizes, int n_in,
                              void* d_out, int out_size, void* d_ws, size_t ws_size,
                              hipStream_t stream){
  (void)in_sizes; (void)n_in; (void)out_size; (void)ws_size;
  const int*   x  = (const int*)d_in[0];
  const float* W  = (const float*)d_in[1];
  const float* Vc = (const float*)d_in[2];
  const float* Ec = (const float*)d_in[3];
  float* out = (float*)d_out;

  char* p = (char*)d_ws;
  auto alloc = [&](size_t bytes)->char*{ char* r = p; p += (bytes+255)&~(size_t)255; return r; };
  float* mats   = (float*)alloc((size_t)NMAT*MSZ*4);           // 138.4 MB
  float* Ws     = (float*)alloc(1048576ull*4);
  float* L11g   = (float*)alloc((size_t)NMAT*4096*4);
  float* U11g   = (float*)alloc((size_t)NMAT*4096*4);
  unsigned short* Ah = (unsigned short*)alloc((size_t)NMAT*PANSZ*2);
  unsigned short* Al = (unsigned short*)alloc((size_t)NMAT*PANSZ*2);
  unsigned short* Bh = (unsigned short*)alloc((size_t)NMAT*PANSZ*2);
  unsigned short* Bl = (unsigned short*)alloc((size_t)NMAT*PANSZ*2);
  float* V      = (float*)alloc(4096*4);
  float* PrInv  = (float*)alloc(32768*4);
  float* partial= (float*)alloc((size_t)32*16384*4);           // 2 MB
  float* y      = (float*)alloc(256);
  float* logdet = (float*)alloc(256);

  k_misc<<<4100,256,0,stream>>>(Vc, V, W, Ws);
  k_pr_y<<<32,256,0,stream>>>(V, x, PrInv, y);
  k_sinkhorn<<<4096,256,0,stream>>>(Ec, V, Ws, PrInv, x, mats, partial);
  k_l0<<<1024,256,0,stream>>>(Ws, mats);
  k_patch<<<dim3(4,32),256,0,stream>>>(mats, partial);
  k_diag<<<NMAT,64,0,stream>>>(mats, L11g, U11g, logdet);

  for(int s=0;s<15;s++){
    int k = 64*s;
    int rem = 1024 - (k+64);
    int nbp = (rem+255)/256;
    k_panel<<<dim3(2*nbp,NMAT),256,0,stream>>>(mats, L11g, U11g, Ah, Al, Bh, Bl, k);
    int nt = (rem+127)/128;
    k_gemm<<<dim3(nt,nt,NMAT),256,0,stream>>>(mats, Ah, Al, Bh, Bl, k, L11g, U11g, logdet);
  }
  k_final<<<1,32,0,stream>>>(y, logdet, out);
}

// Round 6
// 1409.485 us; speedup vs baseline: 1.2927x; 1.2927x over previous
//
#include <hip/hip_runtime.h>
#include <math.h>

#define MSZ   1048576ull  // 1024*1024 elements per matrix slot
#define NMAT  33          // matrix 0 = L0, matrices 1..32 = per-batch L
#define PANSZ 61440       // 960*64 shorts per matrix per panel plane

__device__ __forceinline__ float frcp(float x){ return __builtin_amdgcn_rcpf(x); }

typedef __attribute__((ext_vector_type(8)))  short  bfrag;   // 8 x bf16 (4 VGPR)
typedef __attribute__((ext_vector_type(8)))  unsigned short u16x8;
typedef __attribute__((ext_vector_type(16))) float  f32x16;  // 32x32 acc

__device__ __forceinline__ unsigned short bf16rn(float x){
  unsigned u = __float_as_uint(x);
  unsigned r = u + 0x7fffu + ((u>>16)&1u);
  return (unsigned short)(r>>16);
}
__device__ __forceinline__ float bf2f(unsigned short h){
  return __uint_as_float(((unsigned)h)<<16);
}

// ---------------------------------------------------------------- setup
// blocks 0..3: V = softmax(Vc)    blocks 4..4099: Ws = symmetrized sigmoid(W)
__global__ void k_misc(const float* __restrict__ Vc, float* __restrict__ V,
                       const float* __restrict__ W, float* __restrict__ Ws){
  int t = threadIdx.x;
  if(blockIdx.x < 4){
    int i = blockIdx.x*256 + t;
    float4 v = ((const float4*)Vc)[i];
    float mx = fmaxf(fmaxf(v.x,v.y), fmaxf(v.z,v.w));
    float e0=__expf(v.x-mx), e1=__expf(v.y-mx), e2=__expf(v.z-mx), e3=__expf(v.w-mx);
    float is = 1.f/(e0+e1+e2+e3);
    ((float4*)V)[i] = make_float4(e0*is, e1*is, e2*is, e3*is);
  } else {
    int idx = (blockIdx.x-4)*256 + t;
    int i = idx>>10, j = idx&1023;
    float v = 0.f;
    if(i != j){
      float w = (i>j) ? W[i*1024+j] : W[j*1024+i];
      v = 1.f/(1.f+__expf(-w));
    }
    Ws[idx]=v;
  }
}

__global__ void k_pr_y(const float* __restrict__ V, const int* __restrict__ x,
                       float* __restrict__ PrInv, float* __restrict__ y){
  int b = blockIdx.x, t = threadIdx.x;
  __shared__ float red[256];
  float acc = 0.f;
  for(int i=t; i<1024; i+=256){
    int xv = x[b*1024+i];
    float pr = V[i*4+xv];
    PrInv[b*1024+i] = 1.f/pr;
    acc += logf(pr + 1e-7f);
  }
  red[t]=acc; __syncthreads();
  for(int s=128;s>0;s>>=1){ if(t<s) red[t]+=red[t+s]; __syncthreads(); }
  if(t==0) y[b]=red[0];
}

// ---------------------------------------------------------------- sinkhorn + WP
// 20 iters (4x4 Sinkhorn contracts fast; converged << fp32 ulp by 20 — R5
// verified absmax 0.0).  Writes FINAL off-diagonal Laplacian form 1e-7 - val
// directly; per-(b,row) partial sums wave-reduced into `partial`.
__global__ void __launch_bounds__(256) k_sinkhorn(
    const float* __restrict__ Ec, const float* __restrict__ V,
    const float* __restrict__ Ws, const float* __restrict__ PrInv,
    const int* __restrict__ x, float* __restrict__ mats,
    float* __restrict__ partial){
  int idx = blockIdx.x*256 + threadIdx.x;
  int i = idx>>10, j = idx&1023;   // block covers fixed i, 256 consecutive j
  if(i==0) return;                 // row 0 of WP never needed (whole blocks)
  int t = threadIdx.x;
  int lane = t & 63, wv = t >> 6;
  __shared__ float sE[256][17];
  float E[16];
  {
    const float4* p = (const float4*)(Ec + (size_t)idx*16);
    float4 q0=p[0], q1=p[1], q2=p[2], q3=p[3];
    E[0]=__expf(q0.x); E[1]=__expf(q0.y); E[2]=__expf(q0.z); E[3]=__expf(q0.w);
    E[4]=__expf(q1.x); E[5]=__expf(q1.y); E[6]=__expf(q1.z); E[7]=__expf(q1.w);
    E[8]=__expf(q2.x); E[9]=__expf(q2.y); E[10]=__expf(q2.z); E[11]=__expf(q2.w);
    E[12]=__expf(q3.x);E[13]=__expf(q3.y);E[14]=__expf(q3.z); E[15]=__expf(q3.w);
  }
  float s0=0.f;
  #pragma unroll
  for(int q=0;q<16;q++) s0+=E[q];
  float is0 = frcp(s0);
  #pragma unroll
  for(int q=0;q<16;q++) E[q]*=is0;
  float av[4], bv[4];
  {
    float4 va = ((const float4*)V)[i];
    av[0]=va.x; av[1]=va.y; av[2]=va.z; av[3]=va.w;
    float4 vb = ((const float4*)V)[j];
    bv[0]=vb.x; bv[1]=vb.y; bv[2]=vb.z; bv[3]=vb.w;
  }
  for(int it=0; it<20; ++it){
    #pragma unroll
    for(int r=0;r<4;r++){
      float rs = E[4*r]+E[4*r+1]+E[4*r+2]+E[4*r+3];
      float sc = av[r]*frcp(rs+1e-7f);
      E[4*r]*=sc; E[4*r+1]*=sc; E[4*r+2]*=sc; E[4*r+3]*=sc;
    }
    #pragma unroll
    for(int c=0;c<4;c++){
      float cs = E[c]+E[4+c]+E[8+c]+E[12+c];
      float sc = bv[c]*frcp(cs+1e-7f);
      E[c]*=sc; E[4+c]*=sc; E[8+c]*=sc; E[12+c]*=sc;
    }
  }
  #pragma unroll
  for(int q=0;q<16;q++) sE[t][q] = fminf(fmaxf(E[q],0.f),1.f);
  float wsij = Ws[idx];                 // 0 on diagonal -> val=0 there
  for(int b=0;b<32;b++){
    int xi = x[b*1024+i];               // uniform per block -> scalar load
    int xj = x[b*1024+j];
    float val = sE[t][(xi<<2)+xj] * wsij * PrInv[b*1024+i] * PrInv[b*1024+j];
    if(j!=0)                            // j==0 exists only in the row sum
      mats[(size_t)(1+b)*MSZ + (size_t)(i-1)*1024 + (j-1)] = 1e-7f - val;
    float r = val;                      // wave-reduce row-sum contribution
    r += __shfl_down(r,32); r += __shfl_down(r,16); r += __shfl_down(r,8);
    r += __shfl_down(r,4);  r += __shfl_down(r,2);  r += __shfl_down(r,1);
    if(lane==0)
      partial[((size_t)b<<14) + ((size_t)(i-1)<<4) + ((blockIdx.x&3)<<2) + wv] = r;
  }
}

// ---------------------------------------------------------------- L0 build
// mats[0] = L0[1:,1:] padded to 1024 (row/col 1023 zero, [1023][1023]=1).
__global__ void k_l0(const float* __restrict__ Ws, float* __restrict__ mats){
  int r = blockIdx.x, t = threadIdx.x;
  float* orow = mats + (size_t)r*1024;
  if(r == 1023){
    float4 o = make_float4(0.f,0.f,0.f,0.f);
    if(t==255) o.w = 1.f;
    ((float4*)orow)[t] = o;
    return;
  }
  const float* wrow = Ws + (size_t)(r+1)*1024;
  float4 v = ((const float4*)wrow)[t];
  __shared__ float red[256];
  red[t] = v.x+v.y+v.z+v.w;             // full 1024-col row sum (Ws diag = 0)
  __syncthreads();
  for(int s=128;s>0;s>>=1){ if(t<s) red[t]+=red[t+s]; __syncthreads(); }
  float rs = red[0];
  float o[4];
  #pragma unroll
  for(int q=0;q<4;q++){
    int c = 4*t+q;
    if(c==r)          o[q] = rs + 1e-7f;
    else if(c < 1023) o[q] = 1e-7f - wrow[c+1];
    else              o[q] = 0.f;
  }
  ((float4*)orow)[t] = make_float4(o[0],o[1],o[2],o[3]);
}

// Patch batch matrices: diagonal = rowsum+1e-7 (from partials), clear padding.
__global__ void k_patch(float* __restrict__ mats, const float* __restrict__ partial){
  int m = blockIdx.y + 1;
  int r = blockIdx.x*256 + threadIdx.x;   // 0..1023
  float* A = mats + (size_t)m*MSZ;
  A[(size_t)r*1024 + 1023] = (r==1023) ? 1.f : 0.f;   // col 1023 (+corner)
  if(r < 1023){
    A[(size_t)1023*1024 + r] = 0.f;                   // row 1023
    const float* pp = partial + (((size_t)(m-1))<<14) + ((size_t)r<<4);
    float s = 0.f;
    #pragma unroll
    for(int q=0;q<16;q++) s += pp[q];
    A[(size_t)r*1024 + r] = s + 1e-7f;
  }
}

// ---------------------------------------------------------------- blocked LU
// 64x64 diagonal-block LU, one wave per matrix, rows in registers + shuffles.
__global__ void __launch_bounds__(64) k_diag(float* __restrict__ mats,
    float* __restrict__ L11g, float* __restrict__ U11g,
    float* __restrict__ logdet, int k){
  int m = blockIdx.x;
  const float* A = mats + (size_t)m*MSZ;
  int t = threadIdx.x;
  float row[64];
  #pragma unroll
  for(int q=0;q<64;q++)
    row[q] = A[(size_t)(k+t)*1024 + k + q];
  float slog = 0.f;
  #pragma unroll
  for(int c=0;c<64;c++){
    float piv = __shfl(row[c], c);
    slog += logf(fabsf(piv));
    float ip = frcp(piv);
    bool below = t > c;
    float lic = below ? row[c]*ip : 0.f;
    row[c] = below ? lic : row[c];
    if(below) L11g[m*4096 + t*64 + c] = lic;
    #pragma unroll
    for(int q=c+1;q<64;q++){
      float uq = __shfl(row[q], c);
      row[q] = fmaf(-lic, uq, row[q]);
    }
  }
  #pragma unroll
  for(int q=0;q<64;q++)
    U11g[m*4096 + t*64 + q] = (q>=t) ? row[q] : 0.f;
  if(t==0){ if(k==0) logdet[m] = slog; else logdet[m] += slog; }
}

// Panel solves; outputs written ONLY as pre-split bf16 hi/lo panels in the
// gemm's [row][k] layout.
__global__ void __launch_bounds__(256) k_panel(float* __restrict__ mats,
    const float* __restrict__ L11g, const float* __restrict__ U11g,
    unsigned short* __restrict__ Ah, unsigned short* __restrict__ Al,
    unsigned short* __restrict__ Bh, unsigned short* __restrict__ Bl, int k){
  int m = blockIdx.y;
  float* A = mats + (size_t)m*MSZ;
  int rem = 1024 - (k+64);
  int nb = (rem + 255) >> 8;
  int t = threadIdx.x;
  float v[64];
  unsigned short* Ph; unsigned short* Pl; int rel; bool act;
  if((int)blockIdx.x < nb){
    // ---- L21 = A21 * U11^-1  (thread per trailing row)
    const float* __restrict__ U = U11g + m*4096;
    rel = blockIdx.x*256 + t;
    act = rel < rem;
    int i = k + 64 + rel;
    size_t base = (size_t)i*1024 + k;
    const float4* pb = (const float4*)(A + (act ? base : 0));
    #pragma unroll
    for(int q4=0;q4<16;q4++){
      float4 w = act ? pb[q4] : make_float4(0.f,0.f,0.f,0.f);
      v[4*q4]=w.x; v[4*q4+1]=w.y; v[4*q4+2]=w.z; v[4*q4+3]=w.w;
    }
    #pragma unroll
    for(int p=0;p<64;p++){
      float xp = v[p]*frcp(U[p*64+p]);
      v[p] = xp;
      #pragma unroll
      for(int q=p+1;q<64;q++) v[q] = fmaf(-xp, U[p*64+q], v[q]);
    }
    Ph = Ah + (size_t)m*PANSZ; Pl = Al + (size_t)m*PANSZ;
  } else {
    // ---- U12 = L11^-1 * A12  (thread per trailing column)
    const float* __restrict__ L = L11g + m*4096;
    rel = (blockIdx.x - nb)*256 + t;
    act = rel < rem;
    int col = k + 64 + rel;
    #pragma unroll
    for(int r=0;r<64;r++) v[r] = act ? A[(size_t)(k+r)*1024 + col] : 0.f;
    #pragma unroll
    for(int r=1;r<64;r++){
      float s = v[r];
      #pragma unroll
      for(int p=0;p<r;p++) s = fmaf(-L[r*64+p], v[p], s);
      v[r] = s;
    }
    Ph = Bh + (size_t)m*PANSZ; Pl = Bl + (size_t)m*PANSZ;
  }
  if(act){
    u16x8* ph = (u16x8*)(Ph + (size_t)rel*64);
    u16x8* pl = (u16x8*)(Pl + (size_t)rel*64);
    #pragma unroll
    for(int q8=0;q8<8;q8++){
      u16x8 h8, l8;
      #pragma unroll
      for(int e=0;e<8;e++){
        float xv = v[q8*8+e];
        unsigned short h = bf16rn(xv);
        h8[e] = h;
        l8[e] = bf16rn(xv - bf2f(h));
      }
      ph[q8] = h8;
      pl[q8] = l8;
    }
  }
}

// ------------------------------------------------------- MFMA split-bf16 Schur
// A22 -= L21 * U12.  128x128 C tile, 4 waves, K=64 staged in TWO 32-chunks so
// LDS = 32 KB -> 4 blocks/CU (vs 2 at 64 KB): doubles latency hiding for the
// HBM-bound RMW epilogue.  Swizzle koct ^ ((row>>1)&3): <=2-way LDS aliasing
// (free) on both staging writes and b128 frag reads.
__global__ void __launch_bounds__(256) k_gemm(float* __restrict__ mats,
    const unsigned short* __restrict__ Ah, const unsigned short* __restrict__ Al,
    const unsigned short* __restrict__ Bh, const unsigned short* __restrict__ Bl,
    int k){
  int m = blockIdx.z;
  float* A = mats + (size_t)m*MSZ;
  int rem = 1024 - (k+64);
  int i0rel = blockIdx.y*128;
  int j0rel = blockIdx.x*128;
  __shared__ unsigned short As[2][4096];   // [hi/lo][row*32 + swz(koct)*8]
  __shared__ unsigned short Bs[2][4096];
  int t = threadIdx.x;
  int lane = t & 63, wvi = t >> 6;
  int wr = wvi >> 1, wc = wvi & 1;

  const unsigned short* pAh = Ah + (size_t)m*PANSZ;
  const unsigned short* pAl = Al + (size_t)m*PANSZ;
  const unsigned short* pBh = Bh + (size_t)m*PANSZ;
  const unsigned short* pBl = Bl + (size_t)m*PANSZ;

  f32x16 acc[2][2];
  #pragma unroll
  for(int rt=0;rt<2;rt++)
    #pragma unroll
    for(int ct=0;ct<2;ct++)
      #pragma unroll
      for(int q=0;q<16;q++) acc[rt][ct][q] = 0.f;

  int kgrp = lane >> 5;
  for(int ks=0; ks<64; ks+=32){
    if(ks) __syncthreads();
    // stage: 128 rows x 4 octets = 512 chunks per plane-side, 2 per thread
    #pragma unroll
    for(int p=0;p<2;p++){
      int c = t + 256*p;
      int row = c>>2, koct = c&3;
      int lo = row*32 + ((koct ^ ((row>>1)&3))<<3);
      u16x8 z; z = 0;
      {
        int gr = i0rel + row;
        u16x8 vh = (gr<rem) ? *(const u16x8*)(pAh + (size_t)gr*64 + ks + koct*8) : z;
        u16x8 vl = (gr<rem) ? *(const u16x8*)(pAl + (size_t)gr*64 + ks + koct*8) : z;
        *(u16x8*)&As[0][lo] = vh;
        *(u16x8*)&As[1][lo] = vl;
      }
      {
        int gc = j0rel + row;
        u16x8 vh = (gc<rem) ? *(const u16x8*)(pBh + (size_t)gc*64 + ks + koct*8) : z;
        u16x8 vl = (gc<rem) ? *(const u16x8*)(pBl + (size_t)gc*64 + ks + koct*8) : z;
        *(u16x8*)&Bs[0][lo] = vh;
        *(u16x8*)&Bs[1][lo] = vl;
      }
    }
    __syncthreads();
    #pragma unroll
    for(int kc=0;kc<2;kc++){
      int koct = kc*2 + kgrp;
      bfrag ah[2], al[2], bh[2], bl[2];
      #pragma unroll
      for(int rt=0;rt<2;rt++){
        int row = wr*64 + rt*32 + (lane&31);
        int ad = row*32 + ((koct ^ ((row>>1)&3))<<3);
        ah[rt] = *(const bfrag*)&As[0][ad];
        al[rt] = *(const bfrag*)&As[1][ad];
      }
      #pragma unroll
      for(int ct=0;ct<2;ct++){
        int col = wc*64 + ct*32 + (lane&31);
        int ad = col*32 + ((koct ^ ((col>>1)&3))<<3);
        bh[ct] = *(const bfrag*)&Bs[0][ad];
        bl[ct] = *(const bfrag*)&Bs[1][ad];
      }
      #pragma unroll
      for(int rt=0;rt<2;rt++)
        #pragma unroll
        for(int ct=0;ct<2;ct++){
          acc[rt][ct] = __builtin_amdgcn_mfma_f32_32x32x16_bf16(ah[rt], bh[ct], acc[rt][ct], 0,0,0);
          acc[rt][ct] = __builtin_amdgcn_mfma_f32_32x32x16_bf16(ah[rt], bl[ct], acc[rt][ct], 0,0,0);
          acc[rt][ct] = __builtin_amdgcn_mfma_f32_32x32x16_bf16(al[rt], bh[ct], acc[rt][ct], 0,0,0);
        }
    }
  }

  // C RMW epilogue (C/D layout: col=lane&31, row=(reg&3)+8*(reg>>2)+4*(lane>>5))
  // No barrier before this: waves drain into memory phase independently.
  int r0 = k + 64;
  #pragma unroll
  for(int rt=0;rt<2;rt++){
    int rowblk = i0rel + wr*64 + rt*32;
    if(rowblk >= rem) continue;
    #pragma unroll
    for(int ct=0;ct<2;ct++){
      int colblk = j0rel + wc*64 + ct*32;
      if(colblk >= rem) continue;
      int col = r0 + colblk + (lane&31);
      int rbase = r0 + rowblk + ((lane>>5)<<2);
      #pragma unroll
      for(int reg=0;reg<16;reg++){
        int row = rbase + (reg&3) + ((reg>>2)<<3);
        float* pc = A + (size_t)row*1024 + col;
        *pc -= acc[rt][ct][reg];
      }
    }
  }
}

__global__ void k_final(const float* __restrict__ y, const float* __restrict__ logdet,
                        float* __restrict__ out){
  int b = threadIdx.x;
  if(b<32) out[b] = y[b] + logdet[1+b] - logdet[0];
}

// ---------------------------------------------------------------- launch
extern "C" void kernel_launch(void* const* d_in, const int* in_sizes, int n_in,
                              void* d_out, int out_size, void* d_ws, size_t ws_size,
                              hipStream_t stream){
  (void)in_sizes; (void)n_in; (void)out_size; (void)ws_size;
  const int*   x  = (const int*)d_in[0];
  const float* W  = (const float*)d_in[1];
  const float* Vc = (const float*)d_in[2];
  const float* Ec = (const float*)d_in[3];
  float* out = (float*)d_out;

  char* p = (char*)d_ws;
  auto alloc = [&](size_t bytes)->char*{ char* r = p; p += (bytes+255)&~(size_t)255; return r; };
  float* mats   = (float*)alloc((size_t)NMAT*MSZ*4);           // 138.4 MB
  float* Ws     = (float*)alloc(1048576ull*4);
  float* L11g   = (float*)alloc((size_t)NMAT*4096*4);
  float* U11g   = (float*)alloc((size_t)NMAT*4096*4);
  unsigned short* Ah = (unsigned short*)alloc((size_t)NMAT*PANSZ*2);
  unsigned short* Al = (unsigned short*)alloc((size_t)NMAT*PANSZ*2);
  unsigned short* Bh = (unsigned short*)alloc((size_t)NMAT*PANSZ*2);
  unsigned short* Bl = (unsigned short*)alloc((size_t)NMAT*PANSZ*2);
  float* V      = (float*)alloc(4096*4);
  float* PrInv  = (float*)alloc(32768*4);
  float* partial= (float*)alloc((size_t)32*16384*4);           // 2 MB
  float* y      = (float*)alloc(256);
  float* logdet = (float*)alloc(256);

  k_misc<<<4100,256,0,stream>>>(Vc, V, W, Ws);
  k_pr_y<<<32,256,0,stream>>>(V, x, PrInv, y);
  k_sinkhorn<<<4096,256,0,stream>>>(Ec, V, Ws, PrInv, x, mats, partial);
  k_l0<<<1024,256,0,stream>>>(Ws, mats);
  k_patch<<<dim3(4,32),256,0,stream>>>(mats, partial);

  for(int s=0;s<16;s++){
    int k = 64*s;
    k_diag<<<NMAT,64,0,stream>>>(mats, L11g, U11g, logdet, k);
    int rem = 1024 - (k+64);
    if(rem > 0){
      int nbp = (rem+255)/256;
      k_panel<<<dim3(2*nbp,NMAT),256,0,stream>>>(mats, L11g, U11g, Ah, Al, Bh, Bl, k);
      int nt = (rem+127)/128;
      k_gemm<<<dim3(nt,nt,NMAT),256,0,stream>>>(mats, Ah, Al, Bh, Bl, k);
    }
  }
  k_final<<<1,32,0,stream>>>(y, logdet, out);
}

// Round 7
// 1200.320 us; speedup vs baseline: 1.5179x; 1.1743x over previous
//
#include <hip/hip_runtime.h>
#include <math.h>

#define MSZ   1048576ull  // 1024*1024 elements per matrix slot
#define NMAT  33          // matrix 0 = L0, matrices 1..32 = per-batch L
#define PANSZ 61440       // 960*64 shorts per matrix per panel plane
#define NSINK 14

__device__ __forceinline__ float frcp(float x){ return __builtin_amdgcn_rcpf(x); }

typedef __attribute__((ext_vector_type(8)))  short  bfrag;   // 8 x bf16 (4 VGPR)
typedef __attribute__((ext_vector_type(8)))  unsigned short u16x8;
typedef __attribute__((ext_vector_type(16))) float  f32x16;  // 32x32 acc

__device__ __forceinline__ unsigned short bf16rn(float x){
  unsigned u = __float_as_uint(x);
  unsigned r = u + 0x7fffu + ((u>>16)&1u);
  return (unsigned short)(r>>16);
}
__device__ __forceinline__ float bf2f(unsigned short h){
  return __uint_as_float(((unsigned)h)<<16);
}

// ---------------------------------------------------------------- setup
// blocks 0..3: V = softmax(Vc)    blocks 4..4099: Ws = symmetrized sigmoid(W)
__global__ void k_misc(const float* __restrict__ Vc, float* __restrict__ V,
                       const float* __restrict__ W, float* __restrict__ Ws){
  int t = threadIdx.x;
  if(blockIdx.x < 4){
    int i = blockIdx.x*256 + t;
    float4 v = ((const float4*)Vc)[i];
    float mx = fmaxf(fmaxf(v.x,v.y), fmaxf(v.z,v.w));
    float e0=__expf(v.x-mx), e1=__expf(v.y-mx), e2=__expf(v.z-mx), e3=__expf(v.w-mx);
    float is = 1.f/(e0+e1+e2+e3);
    ((float4*)V)[i] = make_float4(e0*is, e1*is, e2*is, e3*is);
  } else {
    int idx = (blockIdx.x-4)*256 + t;
    int i = idx>>10, j = idx&1023;
    float v = 0.f;
    if(i != j){
      float w = (i>j) ? W[i*1024+j] : W[j*1024+i];
      v = 1.f/(1.f+__expf(-w));
    }
    Ws[idx]=v;
  }
}

__global__ void k_pr_y(const float* __restrict__ V, const int* __restrict__ x,
                       float* __restrict__ PrInv, float* __restrict__ y){
  int b = blockIdx.x, t = threadIdx.x;
  __shared__ float red[256];
  float acc = 0.f;
  for(int i=t; i<1024; i+=256){
    int xv = x[b*1024+i];
    float pr = V[i*4+xv];
    PrInv[b*1024+i] = 1.f/pr;
    acc += logf(pr + 1e-7f);
  }
  red[t]=acc; __syncthreads();
  for(int s=128;s>0;s>>=1){ if(t<s) red[t]+=red[t+s]; __syncthreads(); }
  if(t==0) y[b]=red[0];
}

// ---------------------------------------------------------------- sinkhorn + WP
// NSINK iters (linear contraction; fixpoint reached << fp32 ulp well before 20
// — R5/R6 absmax 0.0).  Writes FINAL off-diagonal Laplacian form 1e-7 - val;
// per-(b,row) partial sums wave-reduced into `partial`.
__global__ void __launch_bounds__(256) k_sinkhorn(
    const float* __restrict__ Ec, const float* __restrict__ V,
    const float* __restrict__ Ws, const float* __restrict__ PrInv,
    const int* __restrict__ x, float* __restrict__ mats,
    float* __restrict__ partial){
  int idx = blockIdx.x*256 + threadIdx.x;
  int i = idx>>10, j = idx&1023;   // block covers fixed i, 256 consecutive j
  if(i==0) return;                 // row 0 of WP never needed (whole blocks)
  int t = threadIdx.x;
  int lane = t & 63, wv = t >> 6;
  __shared__ float sE[256][17];
  float E[16];
  {
    const float4* p = (const float4*)(Ec + (size_t)idx*16);
    float4 q0=p[0], q1=p[1], q2=p[2], q3=p[3];
    E[0]=__expf(q0.x); E[1]=__expf(q0.y); E[2]=__expf(q0.z); E[3]=__expf(q0.w);
    E[4]=__expf(q1.x); E[5]=__expf(q1.y); E[6]=__expf(q1.z); E[7]=__expf(q1.w);
    E[8]=__expf(q2.x); E[9]=__expf(q2.y); E[10]=__expf(q2.z); E[11]=__expf(q2.w);
    E[12]=__expf(q3.x);E[13]=__expf(q3.y);E[14]=__expf(q3.z); E[15]=__expf(q3.w);
  }
  float s0=0.f;
  #pragma unroll
  for(int q=0;q<16;q++) s0+=E[q];
  float is0 = frcp(s0);
  #pragma unroll
  for(int q=0;q<16;q++) E[q]*=is0;
  float av[4], bv[4];
  {
    float4 va = ((const float4*)V)[i];
    av[0]=va.x; av[1]=va.y; av[2]=va.z; av[3]=va.w;
    float4 vb = ((const float4*)V)[j];
    bv[0]=vb.x; bv[1]=vb.y; bv[2]=vb.z; bv[3]=vb.w;
  }
  for(int it=0; it<NSINK; ++it){
    #pragma unroll
    for(int r=0;r<4;r++){
      float rs = E[4*r]+E[4*r+1]+E[4*r+2]+E[4*r+3];
      float sc = av[r]*frcp(rs+1e-7f);
      E[4*r]*=sc; E[4*r+1]*=sc; E[4*r+2]*=sc; E[4*r+3]*=sc;
    }
    #pragma unroll
    for(int c=0;c<4;c++){
      float cs = E[c]+E[4+c]+E[8+c]+E[12+c];
      float sc = bv[c]*frcp(cs+1e-7f);
      E[c]*=sc; E[4+c]*=sc; E[8+c]*=sc; E[12+c]*=sc;
    }
  }
  #pragma unroll
  for(int q=0;q<16;q++) sE[t][q] = fminf(fmaxf(E[q],0.f),1.f);
  float wsij = Ws[idx];                 // 0 on diagonal -> val=0 there
  for(int b=0;b<32;b++){
    int xi = x[b*1024+i];               // uniform per block -> scalar load
    int xj = x[b*1024+j];
    float val = sE[t][(xi<<2)+xj] * wsij * PrInv[b*1024+i] * PrInv[b*1024+j];
    if(j!=0)                            // j==0 exists only in the row sum
      mats[(size_t)(1+b)*MSZ + (size_t)(i-1)*1024 + (j-1)] = 1e-7f - val;
    float r = val;                      // wave-reduce row-sum contribution
    r += __shfl_down(r,32); r += __shfl_down(r,16); r += __shfl_down(r,8);
    r += __shfl_down(r,4);  r += __shfl_down(r,2);  r += __shfl_down(r,1);
    if(lane==0)
      partial[((size_t)b<<14) + ((size_t)(i-1)<<4) + ((blockIdx.x&3)<<2) + wv] = r;
  }
}

// ---------------------------------------------------------------- L0 build
__global__ void k_l0(const float* __restrict__ Ws, float* __restrict__ mats){
  int r = blockIdx.x, t = threadIdx.x;
  float* orow = mats + (size_t)r*1024;
  if(r == 1023){
    float4 o = make_float4(0.f,0.f,0.f,0.f);
    if(t==255) o.w = 1.f;
    ((float4*)orow)[t] = o;
    return;
  }
  const float* wrow = Ws + (size_t)(r+1)*1024;
  float4 v = ((const float4*)wrow)[t];
  __shared__ float red[256];
  red[t] = v.x+v.y+v.z+v.w;             // full 1024-col row sum (Ws diag = 0)
  __syncthreads();
  for(int s=128;s>0;s>>=1){ if(t<s) red[t]+=red[t+s]; __syncthreads(); }
  float rs = red[0];
  float o[4];
  #pragma unroll
  for(int q=0;q<4;q++){
    int c = 4*t+q;
    if(c==r)          o[q] = rs + 1e-7f;
    else if(c < 1023) o[q] = 1e-7f - wrow[c+1];
    else              o[q] = 0.f;
  }
  ((float4*)orow)[t] = make_float4(o[0],o[1],o[2],o[3]);
}

// Patch batch matrices: diagonal = rowsum+1e-7 (from partials), clear padding.
__global__ void k_patch(float* __restrict__ mats, const float* __restrict__ partial){
  int m = blockIdx.y + 1;
  int r = blockIdx.x*256 + threadIdx.x;   // 0..1023
  float* A = mats + (size_t)m*MSZ;
  A[(size_t)r*1024 + 1023] = (r==1023) ? 1.f : 0.f;   // col 1023 (+corner)
  if(r < 1023){
    A[(size_t)1023*1024 + r] = 0.f;                   // row 1023
    const float* pp = partial + (((size_t)(m-1))<<14) + ((size_t)r<<4);
    float s = 0.f;
    #pragma unroll
    for(int q=0;q<16;q++) s += pp[q];
    A[(size_t)r*1024 + r] = s + 1e-7f;
  }
}

// ---------------------------------------------------------------- LU panel
// Wave 0 of EVERY block computes the 64x64 diagonal LU (redundantly; ~3.5 us
// shuffle chain, overlapped across blocks/CUs) into LDS; block (0,m) also
// updates logdet.  Then all 256 threads do the L21/U12 solves reading L/U via
// LDS broadcast.  Outputs only as pre-split bf16 hi/lo panels.
__global__ void __launch_bounds__(256) k_panel(float* __restrict__ mats,
    unsigned short* __restrict__ Ah, unsigned short* __restrict__ Al,
    unsigned short* __restrict__ Bh, unsigned short* __restrict__ Bl,
    float* __restrict__ logdet, int k){
  int m = blockIdx.y;
  float* A = mats + (size_t)m*MSZ;
  int rem = 1024 - (k+64);
  int nb = (rem + 255) >> 8;
  int t = threadIdx.x;
  int lane = t & 63, wvi = t >> 6;
  __shared__ float Ld[4096];   // strictly-lower L11 (unit diag implied)
  __shared__ float Ud[4096];   // U11 upper incl diag

  if(wvi==0){
    float row[64];
    #pragma unroll
    for(int q=0;q<64;q++)
      row[q] = A[(size_t)(k+lane)*1024 + k + q];
    float slog = 0.f;
    #pragma unroll
    for(int c=0;c<64;c++){
      float piv = __shfl(row[c], c);
      slog += logf(fabsf(piv));
      float ip = frcp(piv);
      bool below = lane > c;
      float lic = below ? row[c]*ip : 0.f;
      row[c] = below ? lic : row[c];
      if(below) Ld[lane*64 + c] = lic;
      #pragma unroll
      for(int q=c+1;q<64;q++){
        float uq = __shfl(row[q], c);
        row[q] = fmaf(-lic, uq, row[q]);
      }
    }
    #pragma unroll
    for(int q=0;q<64;q++)
      if(q>=lane) Ud[lane*64 + q] = row[q];
    if(lane==0 && blockIdx.x==0){
      if(k==0) logdet[m] = slog; else logdet[m] += slog;
    }
  }
  __syncthreads();

  float v[64];
  unsigned short* Ph; unsigned short* Pl; int rel; bool act;
  if((int)blockIdx.x < nb){
    // ---- L21 = A21 * U11^-1  (thread per trailing row)
    rel = blockIdx.x*256 + t;
    act = rel < rem;
    int i = k + 64 + rel;
    size_t base = (size_t)i*1024 + k;
    const float4* pb = (const float4*)(A + (act ? base : 0));
    #pragma unroll
    for(int q4=0;q4<16;q4++){
      float4 w = act ? pb[q4] : make_float4(0.f,0.f,0.f,0.f);
      v[4*q4]=w.x; v[4*q4+1]=w.y; v[4*q4+2]=w.z; v[4*q4+3]=w.w;
    }
    #pragma unroll
    for(int p=0;p<64;p++){
      float xp = v[p]*frcp(Ud[p*64+p]);
      v[p] = xp;
      #pragma unroll
      for(int q=p+1;q<64;q++) v[q] = fmaf(-xp, Ud[p*64+q], v[q]);
    }
    Ph = Ah + (size_t)m*PANSZ; Pl = Al + (size_t)m*PANSZ;
  } else {
    // ---- U12 = L11^-1 * A12  (thread per trailing column)
    rel = (blockIdx.x - nb)*256 + t;
    act = rel < rem;
    int col = k + 64 + rel;
    #pragma unroll
    for(int r=0;r<64;r++) v[r] = act ? A[(size_t)(k+r)*1024 + col] : 0.f;
    #pragma unroll
    for(int r=1;r<64;r++){
      float s = v[r];
      #pragma unroll
      for(int p=0;p<r;p++) s = fmaf(-Ld[r*64+p], v[p], s);
      v[r] = s;
    }
    Ph = Bh + (size_t)m*PANSZ; Pl = Bl + (size_t)m*PANSZ;
  }
  if(act){
    u16x8* ph = (u16x8*)(Ph + (size_t)rel*64);
    u16x8* pl = (u16x8*)(Pl + (size_t)rel*64);
    #pragma unroll
    for(int q8=0;q8<8;q8++){
      u16x8 h8, l8;
      #pragma unroll
      for(int e=0;e<8;e++){
        float xv = v[q8*8+e];
        unsigned short h = bf16rn(xv);
        h8[e] = h;
        l8[e] = bf16rn(xv - bf2f(h));
      }
      ph[q8] = h8;
      pl[q8] = l8;
    }
  }
}

// Final 64x64 block (k=960): logdet contribution only.
__global__ void __launch_bounds__(64) k_ld(const float* __restrict__ mats,
                                           float* __restrict__ logdet){
  int m = blockIdx.x, t = threadIdx.x;
  const float* A = mats + (size_t)m*MSZ;
  float row[64];
  #pragma unroll
  for(int q=0;q<64;q++)
    row[q] = A[(size_t)(960+t)*1024 + 960 + q];
  float slog = 0.f;
  #pragma unroll
  for(int c=0;c<64;c++){
    float piv = __shfl(row[c], c);
    slog += logf(fabsf(piv));
    float ip = frcp(piv);
    bool below = t > c;
    float lic = below ? row[c]*ip : 0.f;
    #pragma unroll
    for(int q=c+1;q<64;q++){
      float uq = __shfl(row[q], c);
      row[q] = fmaf(-lic, uq, row[q]);
    }
  }
  if(t==0) logdet[m] += slog;
}

// ------------------------------------------------------- MFMA split-bf16 Schur
// A22 -= L21 * U12.  128x128 C tile, 4 waves, K=64 in two 32-chunks (32 KB LDS
// -> 4 blocks/CU).  Stage-1 global loads issued before stage-0's barrier so
// they overlap stage-0 MFMAs.  Swizzle koct ^ ((row>>1)&3): <=2-way aliasing.
__global__ void __launch_bounds__(256) k_gemm(float* __restrict__ mats,
    const unsigned short* __restrict__ Ah, const unsigned short* __restrict__ Al,
    const unsigned short* __restrict__ Bh, const unsigned short* __restrict__ Bl,
    int k){
  int m = blockIdx.z;
  float* A = mats + (size_t)m*MSZ;
  int rem = 1024 - (k+64);
  int i0rel = blockIdx.y*128;
  int j0rel = blockIdx.x*128;
  __shared__ unsigned short As[2][4096];   // [hi/lo][row*32 + swz(koct)*8]
  __shared__ unsigned short Bs[2][4096];
  int t = threadIdx.x;
  int lane = t & 63, wvi = t >> 6;
  int wr = wvi >> 1, wc = wvi & 1;

  const unsigned short* pAh = Ah + (size_t)m*PANSZ;
  const unsigned short* pAl = Al + (size_t)m*PANSZ;
  const unsigned short* pBh = Bh + (size_t)m*PANSZ;
  const unsigned short* pBl = Bl + (size_t)m*PANSZ;

  int rowA[2], koctA[2], ldsOff[2];
  bool vA[2], vB[2];
  size_t offA[2], offB[2];
  #pragma unroll
  for(int p=0;p<2;p++){
    int c = t + 256*p;
    int row = c>>2, koct = c&3;
    rowA[p]=row; koctA[p]=koct;
    ldsOff[p] = row*32 + ((koct ^ ((row>>1)&3))<<3);
    vA[p] = (i0rel+row) < rem;
    vB[p] = (j0rel+row) < rem;
    offA[p] = (size_t)(i0rel+row)*64 + koct*8;
    offB[p] = (size_t)(j0rel+row)*64 + koct*8;
  }
  u16x8 z; z = 0;

  // stage 0 loads -> LDS
  #pragma unroll
  for(int p=0;p<2;p++){
    u16x8 ah = vA[p] ? *(const u16x8*)(pAh + offA[p]) : z;
    u16x8 al = vA[p] ? *(const u16x8*)(pAl + offA[p]) : z;
    u16x8 bh = vB[p] ? *(const u16x8*)(pBh + offB[p]) : z;
    u16x8 bl = vB[p] ? *(const u16x8*)(pBl + offB[p]) : z;
    *(u16x8*)&As[0][ldsOff[p]] = ah;
    *(u16x8*)&As[1][ldsOff[p]] = al;
    *(u16x8*)&Bs[0][ldsOff[p]] = bh;
    *(u16x8*)&Bs[1][ldsOff[p]] = bl;
  }
  // stage 1 loads issued NOW (land in regs while stage 0 computes)
  u16x8 p1[8];
  #pragma unroll
  for(int p=0;p<2;p++){
    p1[4*p+0] = vA[p] ? *(const u16x8*)(pAh + offA[p] + 32) : z;
    p1[4*p+1] = vA[p] ? *(const u16x8*)(pAl + offA[p] + 32) : z;
    p1[4*p+2] = vB[p] ? *(const u16x8*)(pBh + offB[p] + 32) : z;
    p1[4*p+3] = vB[p] ? *(const u16x8*)(pBl + offB[p] + 32) : z;
  }
  __syncthreads();

  f32x16 acc[2][2];
  #pragma unroll
  for(int rt=0;rt<2;rt++)
    #pragma unroll
    for(int ct=0;ct<2;ct++)
      #pragma unroll
      for(int q=0;q<16;q++) acc[rt][ct][q] = 0.f;

  int kgrp = lane >> 5;
  #pragma unroll
  for(int ks=0; ks<2; ks++){
    #pragma unroll
    for(int kc=0;kc<2;kc++){
      int koct = kc*2 + kgrp;
      bfrag ah[2], al[2], bh[2], bl[2];
      #pragma unroll
      for(int rt=0;rt<2;rt++){
        int row = wr*64 + rt*32 + (lane&31);
        int ad = row*32 + ((koct ^ ((row>>1)&3))<<3);
        ah[rt] = *(const bfrag*)&As[0][ad];
        al[rt] = *(const bfrag*)&As[1][ad];
      }
      #pragma unroll
      for(int ct=0;ct<2;ct++){
        int col = wc*64 + ct*32 + (lane&31);
        int ad = col*32 + ((koct ^ ((col>>1)&3))<<3);
        bh[ct] = *(const bfrag*)&Bs[0][ad];
        bl[ct] = *(const bfrag*)&Bs[1][ad];
      }
      #pragma unroll
      for(int rt=0;rt<2;rt++)
        #pragma unroll
        for(int ct=0;ct<2;ct++){
          acc[rt][ct] = __builtin_amdgcn_mfma_f32_32x32x16_bf16(ah[rt], bh[ct], acc[rt][ct], 0,0,0);
          acc[rt][ct] = __builtin_amdgcn_mfma_f32_32x32x16_bf16(ah[rt], bl[ct], acc[rt][ct], 0,0,0);
          acc[rt][ct] = __builtin_amdgcn_mfma_f32_32x32x16_bf16(al[rt], bh[ct], acc[rt][ct], 0,0,0);
        }
    }
    if(ks==0){
      __syncthreads();   // stage-0 reads done
      #pragma unroll
      for(int p=0;p<2;p++){
        *(u16x8*)&As[0][ldsOff[p]] = p1[4*p+0];
        *(u16x8*)&As[1][ldsOff[p]] = p1[4*p+1];
        *(u16x8*)&Bs[0][ldsOff[p]] = p1[4*p+2];
        *(u16x8*)&Bs[1][ldsOff[p]] = p1[4*p+3];
      }
      __syncthreads();
    }
  }

  // C RMW epilogue (C/D layout: col=lane&31, row=(reg&3)+8*(reg>>2)+4*(lane>>5))
  int r0 = k + 64;
  #pragma unroll
  for(int rt=0;rt<2;rt++){
    int rowblk = i0rel + wr*64 + rt*32;
    if(rowblk >= rem) continue;
    #pragma unroll
    for(int ct=0;ct<2;ct++){
      int colblk = j0rel + wc*64 + ct*32;
      if(colblk >= rem) continue;
      int col = r0 + colblk + (lane&31);
      int rbase = r0 + rowblk + ((lane>>5)<<2);
      #pragma unroll
      for(int reg=0;reg<16;reg++){
        int row = rbase + (reg&3) + ((reg>>2)<<3);
        float* pc = A + (size_t)row*1024 + col;
        *pc -= acc[rt][ct][reg];
      }
    }
  }
}

__global__ void k_final(const float* __restrict__ y, const float* __restrict__ logdet,
                        float* __restrict__ out){
  int b = threadIdx.x;
  if(b<32) out[b] = y[b] + logdet[1+b] - logdet[0];
}

// ---------------------------------------------------------------- launch
extern "C" void kernel_launch(void* const* d_in, const int* in_sizes, int n_in,
                              void* d_out, int out_size, void* d_ws, size_t ws_size,
                              hipStream_t stream){
  (void)in_sizes; (void)n_in; (void)out_size; (void)ws_size;
  const int*   x  = (const int*)d_in[0];
  const float* W  = (const float*)d_in[1];
  const float* Vc = (const float*)d_in[2];
  const float* Ec = (const float*)d_in[3];
  float* out = (float*)d_out;

  char* p = (char*)d_ws;
  auto alloc = [&](size_t bytes)->char*{ char* r = p; p += (bytes+255)&~(size_t)255; return r; };
  float* mats   = (float*)alloc((size_t)NMAT*MSZ*4);           // 138.4 MB
  float* Ws     = (float*)alloc(1048576ull*4);
  unsigned short* Ah = (unsigned short*)alloc((size_t)NMAT*PANSZ*2);
  unsigned short* Al = (unsigned short*)alloc((size_t)NMAT*PANSZ*2);
  unsigned short* Bh = (unsigned short*)alloc((size_t)NMAT*PANSZ*2);
  unsigned short* Bl = (unsigned short*)alloc((size_t)NMAT*PANSZ*2);
  float* V      = (float*)alloc(4096*4);
  float* PrInv  = (float*)alloc(32768*4);
  float* partial= (float*)alloc((size_t)32*16384*4);           // 2 MB
  float* y      = (float*)alloc(256);
  float* logdet = (float*)alloc(256);

  k_misc<<<4100,256,0,stream>>>(Vc, V, W, Ws);
  k_pr_y<<<32,256,0,stream>>>(V, x, PrInv, y);
  k_sinkhorn<<<4096,256,0,stream>>>(Ec, V, Ws, PrInv, x, mats, partial);
  k_l0<<<1024,256,0,stream>>>(Ws, mats);
  k_patch<<<dim3(4,32),256,0,stream>>>(mats, partial);

  for(int s=0;s<15;s++){
    int k = 64*s;
    int rem = 1024 - (k+64);
    int nbp = (rem+255)/256;
    k_panel<<<dim3(2*nbp,NMAT),256,0,stream>>>(mats, Ah, Al, Bh, Bl, logdet, k);
    int nt = (rem+127)/128;
    k_gemm<<<dim3(nt,nt,NMAT),256,0,stream>>>(mats, Ah, Al, Bh, Bl, k);
  }
  k_ld<<<NMAT,64,0,stream>>>(mats, logdet);
  k_final<<<1,32,0,stream>>>(y, logdet, out);
}